// Round 1
// baseline (400.719 us; speedup 1.0000x reference)
//
#include <hip/hip_runtime.h>

// Problem constants
#define N_TOTAL  65536   // B*H*W = 64*32*32
#define HW_SZ    1024    // H*W
#define CDIM     64      // embedding dim (= C)
#define K_CODES  1024
#define QB       128     // queries per block (k_argmin)
#define KT       128     // code tile (k_argmin)
#define OUT_ELEMS 4194304  // 64*64*32*32

// ws layout (bytes):
//   0     : enorm[1024] float
//   4096  : hist[1024]  uint
//   8192  : sse (float)
//   16384 : idx[65536]  int

// ---------------------------------------------------------------- k_prep ----
__global__ void k_prep(const float* __restrict__ emb, float* __restrict__ enorm,
                       unsigned int* __restrict__ hist, float* __restrict__ sse) {
    int k = blockIdx.x * blockDim.x + threadIdx.x;   // 0..1023
    const float4* row = (const float4*)(emb + k * CDIM);
    float s = 0.f;
#pragma unroll
    for (int i = 0; i < 16; ++i) {
        float4 v = row[i];
        s += v.x * v.x + v.y * v.y + v.z * v.z + v.w * v.w;
    }
    enorm[k] = s;
    hist[k] = 0u;
    if (k == 0) *sse = 0.f;
}

// -------------------------------------------------------------- k_argmin ----
// Block: 256 threads = 16(ty) x 16(tx). Each block: 128 queries.
// Thread (ty,tx): queries ty*8+i (i<8), codes tx*8+j (j<8) per 128-code tile.
// LDS layout swizzle: logical 4-float chunk ch of row q stored at physical
// chunk (ch ^ ((q>>3)&7)) -> x-reads conflict-free, e-reads 2-way (free).
__global__ __launch_bounds__(256, 2)
void k_argmin(const float* __restrict__ x, const float* __restrict__ emb,
              const float* __restrict__ enorm, int* __restrict__ out_idx) {
    __shared__ float xs[QB * CDIM];    // 32 KB
    __shared__ float es[KT * CDIM];    // 32 KB
    __shared__ float ens[K_CODES];     // 4 KB

    const int tid = threadIdx.x;
    const int n0  = blockIdx.x * QB;
    const int b   = n0 >> 10;
    const int hw0 = n0 & 1023;
    const float* xbase = x + b * (CDIM * HW_SZ) + hw0;

    // stage enorm
#pragma unroll
    for (int i = 0; i < 4; ++i) ens[i * 256 + tid] = enorm[i * 256 + tid];

    // stage x tile (transpose (c,hw) -> (q,c)), swizzled
#pragma unroll
    for (int it = 0; it < 8; ++it) {
        int lin = it * 256 + tid;          // 0..2047
        int q   = lin & 127;
        int ch  = lin >> 7;                // 0..15
        const float* src = xbase + ch * 4 * HW_SZ + q;
        float4 v = make_float4(src[0], src[HW_SZ], src[2 * HW_SZ], src[3 * HW_SZ]);
        *(float4*)&xs[q * CDIM + ((ch ^ ((q >> 3) & 7)) << 2)] = v;
    }

    const int tx = tid & 15;
    const int ty = tid >> 4;
    const int gx = ty & 7;
    const int ge = tx & 7;

    float bestd[8];
    int   besti[8];
#pragma unroll
    for (int i = 0; i < 8; ++i) { bestd[i] = 3.4e38f; besti[i] = 0; }

    for (int t = 0; t < 8; ++t) {
        const int kbase = t * KT;
        __syncthreads();   // xs visible (t==0); es from prev tile done being read
        // stage e tile, swizzled
#pragma unroll
        for (int it = 0; it < 8; ++it) {
            int lin = it * 256 + tid;
            int q   = lin & 127;
            int ch  = lin >> 7;
            float4 v = *(const float4*)(emb + (kbase + q) * CDIM + ch * 4);
            *(float4*)&es[q * CDIM + ((ch ^ ((q >> 3) & 7)) << 2)] = v;
        }
        __syncthreads();

        float acc[8][8];
#pragma unroll
        for (int i = 0; i < 8; ++i)
#pragma unroll
            for (int j = 0; j < 8; ++j) acc[i][j] = 0.f;

        for (int ch = 0; ch < 16; ++ch) {
            float4 xf[8], ef[8];
#pragma unroll
            for (int i = 0; i < 8; ++i)
                xf[i] = *(const float4*)&xs[(ty * 8 + i) * CDIM + ((ch ^ gx) << 2)];
#pragma unroll
            for (int j = 0; j < 8; ++j)
                ef[j] = *(const float4*)&es[(tx * 8 + j) * CDIM + ((ch ^ ge) << 2)];
#pragma unroll
            for (int i = 0; i < 8; ++i)
#pragma unroll
                for (int j = 0; j < 8; ++j) {
                    acc[i][j] += xf[i].x * ef[j].x;
                    acc[i][j] += xf[i].y * ef[j].y;
                    acc[i][j] += xf[i].z * ef[j].z;
                    acc[i][j] += xf[i].w * ef[j].w;
                }
        }

        // distance = ||e||^2 - 2*dot  (||x||^2 constant per query), update best
#pragma unroll
        for (int j = 0; j < 8; ++j) {
            int kk  = kbase + tx * 8 + j;
            float en = ens[kk];
#pragma unroll
            for (int i = 0; i < 8; ++i) {
                float d = en - 2.f * acc[i][j];
                if (d < bestd[i]) { bestd[i] = d; besti[i] = kk; }
            }
        }
    }

    // reduce across the 16 tx lanes sharing each query (lex-min on (d, idx))
#pragma unroll
    for (int i = 0; i < 8; ++i) {
        float d = bestd[i];
        int  bi = besti[i];
#pragma unroll
        for (int off = 1; off < 16; off <<= 1) {
            float od = __shfl_xor(d, off, 64);
            int   oi = __shfl_xor(bi, off, 64);
            if (od < d || (od == d && oi < bi)) { d = od; bi = oi; }
        }
        if (tx == 0) out_idx[n0 + ty * 8 + i] = bi;
    }
}

// -------------------------------------------------------------- k_output ----
// gid is the linear (b,c,hw) index of both `inputs` and `quantized`.
__global__ void k_output(const float* __restrict__ x, const float* __restrict__ emb,
                         const int* __restrict__ idx, float* __restrict__ out,
                         float* __restrict__ sse, unsigned int* __restrict__ hist) {
    int gid = blockIdx.x * 256 + threadIdx.x;
    int hw  = gid & 1023;
    int c   = (gid >> 10) & 63;
    int b   = gid >> 16;
    int n   = b * HW_SZ + hw;
    int k   = idx[n];
    float q  = emb[k * CDIM + c];
    float xv = x[gid];
    out[gid] = q;
    float dv = q - xv;
    float d2 = dv * dv;

    // block-reduce d2 -> one atomic per block
    __shared__ float red[4];
#pragma unroll
    for (int off = 32; off; off >>= 1) d2 += __shfl_down(d2, off, 64);
    if ((threadIdx.x & 63) == 0) red[threadIdx.x >> 6] = d2;
    __syncthreads();
    if (threadIdx.x == 0) atomicAdd(sse, red[0] + red[1] + red[2] + red[3]);

    // histogram: exactly the c==0 blocks cover every n once (block-uniform branch)
    if (c == 0) atomicAdd(&hist[k], 1u);
}

// --------------------------------------------------------------- k_final ----
__global__ void k_final(const unsigned int* __restrict__ hist,
                        const float* __restrict__ sse, float* __restrict__ out2) {
    int tid = threadIdx.x;   // 256
    float s = 0.f;
#pragma unroll
    for (int i = 0; i < 4; ++i) {
        float p = (float)hist[i * 256 + tid] * (1.0f / 65536.0f);
        s += p * logf(p + 1e-10f);
    }
#pragma unroll
    for (int off = 32; off; off >>= 1) s += __shfl_down(s, off, 64);
    __shared__ float red[4];
    if ((tid & 63) == 0) red[tid >> 6] = s;
    __syncthreads();
    if (tid == 0) {
        float tot = red[0] + red[1] + red[2] + red[3];
        out2[0] = 1.25f * (*sse) * (1.0f / (float)OUT_ELEMS);  // loss
        out2[1] = expf(-tot);                                   // perplexity
    }
}

// ---------------------------------------------------------------- launch ----
extern "C" void kernel_launch(void* const* d_in, const int* in_sizes, int n_in,
                              void* d_out, int out_size, void* d_ws, size_t ws_size,
                              hipStream_t stream) {
    const float* x   = (const float*)d_in[0];   // [64,64,32,32]
    const float* emb = (const float*)d_in[1];   // [1024,64]
    float* out = (float*)d_out;                 // 4194304 + 2
    char* ws = (char*)d_ws;
    float*        enorm = (float*)(ws);
    unsigned int* hist  = (unsigned int*)(ws + 4096);
    float*        sse   = (float*)(ws + 8192);
    int*          idx   = (int*)(ws + 16384);

    k_prep  <<<K_CODES / 256, 256, 0, stream>>>(emb, enorm, hist, sse);
    k_argmin<<<N_TOTAL / QB,  256, 0, stream>>>(x, emb, enorm, idx);
    k_output<<<OUT_ELEMS / 256, 256, 0, stream>>>(x, emb, idx, out, sse, hist);
    k_final <<<1, 256, 0, stream>>>(hist, sse, out + OUT_ELEMS);
}

// Round 2
// 210.765 us; speedup vs baseline: 1.9013x; 1.9013x over previous
//
#include <hip/hip_runtime.h>

// Problem constants
#define N_TOTAL  65536   // B*H*W = 64*32*32
#define HW_SZ    1024    // H*W
#define CDIM     64      // embedding dim (= C)
#define K_CODES  1024
#define QB       128     // queries per block (k_argmin)
#define KT       128     // code tile (k_argmin)
#define OUT_ELEMS 4194304  // 64*64*32*32
#define NBLK_OUT (OUT_ELEMS / 256)   // 16384

// ws layout (bytes):
//   0      : enorm[1024] float
//   4096   : hist[1024]  uint
//   16384  : partials[16384] float   (per-block SSE, no atomics)
//   131072 : idx[65536]  int

// ---------------------------------------------------------------- k_prep ----
__global__ void k_prep(const float* __restrict__ emb, float* __restrict__ enorm,
                       unsigned int* __restrict__ hist) {
    int k = blockIdx.x * blockDim.x + threadIdx.x;   // 0..1023
    const float4* row = (const float4*)(emb + k * CDIM);
    float s = 0.f;
#pragma unroll
    for (int i = 0; i < 16; ++i) {
        float4 v = row[i];
        s += v.x * v.x + v.y * v.y + v.z * v.z + v.w * v.w;
    }
    enorm[k] = s;
    hist[k] = 0u;
}

// -------------------------------------------------------------- k_argmin ----
// (unchanged this round — need clean counters for it)
__global__ __launch_bounds__(256, 2)
void k_argmin(const float* __restrict__ x, const float* __restrict__ emb,
              const float* __restrict__ enorm, int* __restrict__ out_idx) {
    __shared__ float xs[QB * CDIM];    // 32 KB
    __shared__ float es[KT * CDIM];    // 32 KB
    __shared__ float ens[K_CODES];     // 4 KB

    const int tid = threadIdx.x;
    const int n0  = blockIdx.x * QB;
    const int b   = n0 >> 10;
    const int hw0 = n0 & 1023;
    const float* xbase = x + b * (CDIM * HW_SZ) + hw0;

#pragma unroll
    for (int i = 0; i < 4; ++i) ens[i * 256 + tid] = enorm[i * 256 + tid];

#pragma unroll
    for (int it = 0; it < 8; ++it) {
        int lin = it * 256 + tid;          // 0..2047
        int q   = lin & 127;
        int ch  = lin >> 7;                // 0..15
        const float* src = xbase + ch * 4 * HW_SZ + q;
        float4 v = make_float4(src[0], src[HW_SZ], src[2 * HW_SZ], src[3 * HW_SZ]);
        *(float4*)&xs[q * CDIM + ((ch ^ ((q >> 3) & 7)) << 2)] = v;
    }

    const int tx = tid & 15;
    const int ty = tid >> 4;
    const int gx = ty & 7;
    const int ge = tx & 7;

    float bestd[8];
    int   besti[8];
#pragma unroll
    for (int i = 0; i < 8; ++i) { bestd[i] = 3.4e38f; besti[i] = 0; }

    for (int t = 0; t < 8; ++t) {
        const int kbase = t * KT;
        __syncthreads();
#pragma unroll
        for (int it = 0; it < 8; ++it) {
            int lin = it * 256 + tid;
            int q   = lin & 127;
            int ch  = lin >> 7;
            float4 v = *(const float4*)(emb + (kbase + q) * CDIM + ch * 4);
            *(float4*)&es[q * CDIM + ((ch ^ ((q >> 3) & 7)) << 2)] = v;
        }
        __syncthreads();

        float acc[8][8];
#pragma unroll
        for (int i = 0; i < 8; ++i)
#pragma unroll
            for (int j = 0; j < 8; ++j) acc[i][j] = 0.f;

        for (int ch = 0; ch < 16; ++ch) {
            float4 xf[8], ef[8];
#pragma unroll
            for (int i = 0; i < 8; ++i)
                xf[i] = *(const float4*)&xs[(ty * 8 + i) * CDIM + ((ch ^ gx) << 2)];
#pragma unroll
            for (int j = 0; j < 8; ++j)
                ef[j] = *(const float4*)&es[(tx * 8 + j) * CDIM + ((ch ^ ge) << 2)];
#pragma unroll
            for (int i = 0; i < 8; ++i)
#pragma unroll
                for (int j = 0; j < 8; ++j) {
                    acc[i][j] += xf[i].x * ef[j].x;
                    acc[i][j] += xf[i].y * ef[j].y;
                    acc[i][j] += xf[i].z * ef[j].z;
                    acc[i][j] += xf[i].w * ef[j].w;
                }
        }

#pragma unroll
        for (int j = 0; j < 8; ++j) {
            int kk  = kbase + tx * 8 + j;
            float en = ens[kk];
#pragma unroll
            for (int i = 0; i < 8; ++i) {
                float d = en - 2.f * acc[i][j];
                if (d < bestd[i]) { bestd[i] = d; besti[i] = kk; }
            }
        }
    }

#pragma unroll
    for (int i = 0; i < 8; ++i) {
        float d = bestd[i];
        int  bi = besti[i];
#pragma unroll
        for (int off = 1; off < 16; off <<= 1) {
            float od = __shfl_xor(d, off, 64);
            int   oi = __shfl_xor(bi, off, 64);
            if (od < d || (od == d && oi < bi)) { d = od; bi = oi; }
        }
        if (tx == 0) out_idx[n0 + ty * 8 + i] = bi;
    }
}

// -------------------------------------------------------------- k_output ----
// Pure gather + write + per-block partial SSE (plain store, NO atomics).
__global__ void k_output(const float* __restrict__ x, const float* __restrict__ emb,
                         const int* __restrict__ idx, float* __restrict__ out,
                         float* __restrict__ partials) {
    int gid = blockIdx.x * 256 + threadIdx.x;
    int hw  = gid & 1023;
    int c   = (gid >> 10) & 63;
    int b   = gid >> 16;
    int n   = b * HW_SZ + hw;
    int k   = idx[n];
    float q  = emb[k * CDIM + c];
    float xv = x[gid];
    out[gid] = q;
    float dv = q - xv;
    float d2 = dv * dv;

    __shared__ float red[4];
#pragma unroll
    for (int off = 32; off; off >>= 1) d2 += __shfl_down(d2, off, 64);
    if ((threadIdx.x & 63) == 0) red[threadIdx.x >> 6] = d2;
    __syncthreads();
    if (threadIdx.x == 0) partials[blockIdx.x] = red[0] + red[1] + red[2] + red[3];
}

// ---------------------------------------------------------------- k_hist ----
// 64 blocks x 256 threads: LDS histogram, then <=64 global atomics per bin.
__global__ void k_hist(const int* __restrict__ idx, unsigned int* __restrict__ hist) {
    __shared__ unsigned int lh[K_CODES];
    int tid = threadIdx.x;
#pragma unroll
    for (int i = 0; i < 4; ++i) lh[i * 256 + tid] = 0u;
    __syncthreads();
    for (int i = blockIdx.x * 256 + tid; i < N_TOTAL; i += 64 * 256)
        atomicAdd(&lh[idx[i]], 1u);
    __syncthreads();
#pragma unroll
    for (int i = 0; i < 4; ++i) {
        unsigned int v = lh[i * 256 + tid];
        if (v) atomicAdd(&hist[i * 256 + tid], v);
    }
}

// --------------------------------------------------------------- k_final ----
__global__ void k_final(const unsigned int* __restrict__ hist,
                        const float* __restrict__ partials, float* __restrict__ out2) {
    int tid = threadIdx.x;   // 256
    // SSE reduce over 16384 partials
    float ss = 0.f;
#pragma unroll
    for (int i = 0; i < 64; ++i) ss += partials[i * 256 + tid];
    // perplexity entropy terms
    float s = 0.f;
#pragma unroll
    for (int i = 0; i < 4; ++i) {
        float p = (float)hist[i * 256 + tid] * (1.0f / 65536.0f);
        s += p * logf(p + 1e-10f);
    }
    __shared__ float redA[4], redB[4];
#pragma unroll
    for (int off = 32; off; off >>= 1) {
        s  += __shfl_down(s, off, 64);
        ss += __shfl_down(ss, off, 64);
    }
    if ((tid & 63) == 0) { redA[tid >> 6] = s; redB[tid >> 6] = ss; }
    __syncthreads();
    if (tid == 0) {
        float tot = redA[0] + redA[1] + redA[2] + redA[3];
        float sse = redB[0] + redB[1] + redB[2] + redB[3];
        out2[0] = 1.25f * sse * (1.0f / (float)OUT_ELEMS);  // loss
        out2[1] = expf(-tot);                                // perplexity
    }
}

// ---------------------------------------------------------------- launch ----
extern "C" void kernel_launch(void* const* d_in, const int* in_sizes, int n_in,
                              void* d_out, int out_size, void* d_ws, size_t ws_size,
                              hipStream_t stream) {
    const float* x   = (const float*)d_in[0];   // [64,64,32,32]
    const float* emb = (const float*)d_in[1];   // [1024,64]
    float* out = (float*)d_out;                 // 4194304 + 2
    char* ws = (char*)d_ws;
    float*        enorm    = (float*)(ws);
    unsigned int* hist     = (unsigned int*)(ws + 4096);
    float*        partials = (float*)(ws + 16384);
    int*          idx      = (int*)(ws + 131072);

    k_prep  <<<K_CODES / 256, 256, 0, stream>>>(emb, enorm, hist);
    k_argmin<<<N_TOTAL / QB,  256, 0, stream>>>(x, emb, enorm, idx);
    k_output<<<NBLK_OUT, 256, 0, stream>>>(x, emb, idx, out, partials);
    k_hist  <<<64, 256, 0, stream>>>(idx, hist);
    k_final <<<1, 256, 0, stream>>>(hist, partials, out + OUT_ELEMS);
}